// Round 1
// baseline (5777.610 us; speedup 1.0000x reference)
//
#include <hip/hip_runtime.h>

typedef unsigned short u16;
typedef __bf16 bf16_t;
typedef bf16_t bf16x8 __attribute__((ext_vector_type(8)));
typedef u16 u16x8 __attribute__((ext_vector_type(8)));
typedef float f32x4 __attribute__((ext_vector_type(4)));

__device__ __forceinline__ u16 f2bf(float f) {
    unsigned u = __builtin_bit_cast(unsigned, f);
    u += 0x7fffu + ((u >> 16) & 1u);   // RNE
    return (u16)(u >> 16);
}
__device__ __forceinline__ float bf2f(u16 h) {
    unsigned u = ((unsigned)h) << 16;
    return __builtin_bit_cast(float, u);
}
__device__ __forceinline__ float fast_tanh(float x) {
    x = fminf(fmaxf(x, -20.f), 20.f);
    float e = __expf(2.f * x);
    return (e - 1.f) * __builtin_amdgcn_rcpf(e + 1.f);
}
__device__ __forceinline__ void gload_lds16(const void* g, void* l) {
    __builtin_amdgcn_global_load_lds((__attribute__((address_space(1))) void*)(g),
                                     (__attribute__((address_space(3))) void*)(l),
                                     16, 0, 0);
}
__device__ __forceinline__ bf16x8 ld8(const u16* p) {
    return __builtin_bit_cast(bf16x8, *(const u16x8*)p);
}

// s_waitcnt immediates (validated on this harness): vmcnt low bits [3:0],
// all other count fields "no wait".
#define VMWAIT8() __builtin_amdgcn_s_waitcnt(0x3F78)
#define VMWAIT4() __builtin_amdgcn_s_waitcnt(0x3F74)
#define VMWAIT0() __builtin_amdgcn_s_waitcnt(0x3F70)
#define MEMFENCE() asm volatile("" ::: "memory")
#define SBAR() do { MEMFENCE(); __builtin_amdgcn_s_barrier(); MEMFENCE(); } while (0)

// Blocked layout: M x N stored as 128x32 tiles, tile (m>>7,n>>5) contiguous
// 4096 elems; interior [kb=(n>>3)&3][row=m&127][n&7] == the LDS staging image.

// ---------------- conversion kernels ----------------

__global__ void cvt_bf16(const float* __restrict__ src, u16* __restrict__ dst, int n4) {
    int i = blockIdx.x * blockDim.x + threadIdx.x;
    if (i < n4) {
        float4 v = ((const float4*)src)[i];
        ushort4 o;
        o.x = f2bf(v.x); o.y = f2bf(v.y); o.z = f2bf(v.z); o.w = f2bf(v.w);
        ((ushort4*)dst)[i] = o;
    }
}

// W: R x C fp32  ->  WT: C x R bf16 (row-major)
__global__ void transpose_cvt(const float* __restrict__ W, u16* __restrict__ WT, int R, int C) {
    __shared__ float tile[32][33];
    int c0 = blockIdx.x * 32, r0 = blockIdx.y * 32;
    int tx = threadIdx.x & 31, ty = threadIdx.x >> 5;  // 32x8
#pragma unroll
    for (int i = 0; i < 32; i += 8)
        tile[ty + i][tx] = W[(size_t)(r0 + ty + i) * C + (c0 + tx)];
    __syncthreads();
#pragma unroll
    for (int i = 0; i < 32; i += 8)
        WT[(size_t)(c0 + ty + i) * R + (r0 + tx)] = f2bf(tile[tx][ty + i]);
}

// row-major bf16 (M x K) -> blocked layout. grid = (M/128)*(K/32), 256 thr.
__global__ void blockify(const u16* __restrict__ src, u16* __restrict__ dst, int K) {
    const int nk = K >> 5;
    const int rb = blockIdx.x / nk, cb = blockIdx.x % nk;
    const int t = threadIdx.x;
    const int kloc = (t & 7) * 4;
    u16* d = dst + (size_t)blockIdx.x * 4096 + ((kloc >> 3) << 10) + (kloc & 7);
    const u16* s = src + (size_t)(rb * 128) * K + cb * 32 + kloc;
#pragma unroll
    for (int p = 0; p < 4; ++p) {
        int row = (t >> 3) + p * 32;
        *(ushort4*)(d + row * 8) = *(const ushort4*)(s + (size_t)row * K);
    }
}

// ---------------- segmented fused NT GEMM phase ----------------
// 256x256 tile, 8 waves (2M x 4N), BK=64, double-buffered 128KB LDS.
// Per K-tile: 4 sub-phases (kk,mh); stage issue staggered by k-half so every
// steady-state wait is vmcnt(8) (one full K-tile of loads stays in flight).
// mode 0 (FWD):  v = tanh(C + bias[n]);            -> outbf [+outf]
// mode 1 (ERR):  v = rsrcb - tanh(C);              -> outbf  (+0.5v^2)
// mode 2 (UPD):  v = rsrcb + 0.1*(C - esub);       -> outbf (in-place ok)
// mode 3 (UPD3): v = 0.9*rsrcf + 0.1*C;            -> outf, outbf (+0.5v^2)

struct Seg {
    const u16* A; const u16* B;
    const u16* rsrcb;          // blocked bf16 (modes 1,2)
    const float* rsrcf;        // f32 row-major (mode 3)
    const float* bias;         // f32 (mode 0)
    const u16* esub;           // blocked bf16 (mode 2)
    float* outf;               // f32 row-major (modes 0(r3),3)
    u16* outbf;                // blocked bf16 (all modes)
    int K, N, blkStart, mode, accum;
};
struct Phase {
    Seg seg[3];
    int bEnd0, bEnd1;
};

#define READ_A(buf, kk, mh) do { \
    const u16* _p = SH + (buf)*16384 + (wr2+(kk))*4096 + aoff + (mh)*512; \
    aR[0] = ld8(_p); aR[1] = ld8(_p+128); aR[2] = ld8(_p+256); aR[3] = ld8(_p+384); \
} while (0)

#define READ_B(buf, kk) do { \
    const u16* _p = SH + 32768 + (buf)*16384 + (wch2+(kk))*4096 + boff; \
    bR[0] = ld8(_p); bR[1] = ld8(_p+128); bR[2] = ld8(_p+256); bR[3] = ld8(_p+384); \
} while (0)

#define MFMA16(mh) do { \
    __builtin_amdgcn_s_setprio(1); \
    _Pragma("unroll") \
    for (int _i = 0; _i < 4; ++_i) { \
        _Pragma("unroll") \
        for (int _n = 0; _n < 4; ++_n) \
            acc[(mh)*4+_i][_n] = __builtin_amdgcn_mfma_f32_16x16x32_bf16( \
                aR[_i], bR[_n], acc[(mh)*4+_i][_n], 0, 0, 0); \
    } \
    __builtin_amdgcn_s_setprio(0); \
} while (0)

__global__ __launch_bounds__(512, 2) void pc_phase(Phase ph, float* __restrict__ errAcc) {
    // [0..32768)  A tiles: 2 buf x 4 sub-blocks(mh*2+ks) x 4096
    // [32768..65536) B tiles, same structure. Epilogue reuses all 128KB as image.
    __shared__ __align__(16) u16 SH[65536];
    __shared__ float red[8];

    const int bid = blockIdx.x;
    const int segi = (bid >= ph.bEnd0 ? 1 : 0) + (bid >= ph.bEnd1 ? 1 : 0);

    const u16* Ab = ph.seg[segi].A;
    const u16* Bb = ph.seg[segi].B;
    const int K = ph.seg[segi].K;
    const int local = bid - ph.seg[segi].blkStart;
    const int bx2 = local >> 4;      // N-tile (weight-major grouping, 16 M-tiles/group)
    const int by2 = local & 15;      // M-tile
    const int nk32 = K >> 5, NT = K >> 6;

    const int tid  = threadIdx.x;
    const int wave = tid >> 6, lane = tid & 63;
    const int q    = lane >> 4, ln = lane & 15;
    const int wr = wave >> 2, wc = wave & 3;      // 2M x 4N wave grid
    const int wr2 = wr * 2, wch2 = (wc >> 1) * 2;
    const int aoff = q * 1024 + ln * 8;
    const int boff = q * 1024 + ((wc & 1) * 64 + ln) * 8;

    const size_t t8 = (size_t)tid * 8;
    const u16* gA0 = Ab + ((size_t)(by2 * 2 + 0) * nk32) * 4096 + t8;
    const u16* gA1 = Ab + ((size_t)(by2 * 2 + 1) * nk32) * 4096 + t8;
    const u16* gB0 = Bb + ((size_t)(bx2 * 2 + 0) * nk32) * 4096 + t8;
    const u16* gB1 = Bb + ((size_t)(bx2 * 2 + 1) * nk32) * 4096 + t8;
    const int wb = wave * 512;

    // one k-half group = 4 sub-blocks (A mh0/mh1, B nh0/nh1), 4 loads/thread
    auto stage = [&](int cb, int buf, int ks) {
        const size_t g = (size_t)cb * 4096;
        u16* a = SH + buf * 16384 + ks * 4096 + wb;
        gload_lds16(gA0 + g, a);
        gload_lds16(gA1 + g, a + 8192);
        gload_lds16(gB0 + g, a + 32768);
        gload_lds16(gB1 + g, a + 32768 + 8192);
    };

    f32x4 acc[8][4];
#pragma unroll
    for (int i = 0; i < 8; ++i)
#pragma unroll
        for (int j = 0; j < 4; ++j)
            acc[i][j] = (f32x4){0.f, 0.f, 0.f, 0.f};

    // prologue: G0(0), G1(0) -> buf0; G0(1) -> buf1   (12 loads in flight)
    stage(0, 0, 0);
    stage(1, 0, 1);
    stage(2, 1, 0);

    bf16x8 aR[4], bR[4];

    for (int t = 0; t < NT - 1; ++t) {
        const int buf = t & 1;
        // P1 (k0, mh0): need G0(t); G1(t)+G0(t+1) stay in flight
        VMWAIT8(); SBAR();
        stage(2 * t + 3, buf ^ 1, 1);          // G1(t+1) -> other buf k1 region
        READ_A(buf, 0, 0); READ_B(buf, 0); MFMA16(0);
        // P2 (k0, mh1)
        SBAR();
        READ_A(buf, 0, 1); MFMA16(1);
        // P3 (k1, mh0): need G1(t); G0(t+1)+G1(t+1) stay in flight
        VMWAIT8(); SBAR();
        if (t + 2 < NT) stage(2 * t + 4, buf, 0);  // G0(t+2) -> this buf k0 region
        READ_A(buf, 1, 0); READ_B(buf, 1); MFMA16(0);
        // P4 (k1, mh1)
        SBAR();
        READ_A(buf, 1, 1); MFMA16(1);
    }
    {   // tail tile (no further staging)
        const int buf = (NT - 1) & 1;
        VMWAIT4(); SBAR();
        READ_A(buf, 0, 0); READ_B(buf, 0); MFMA16(0);
        SBAR();
        READ_A(buf, 0, 1); MFMA16(1);
        VMWAIT0(); SBAR();
        READ_A(buf, 1, 0); READ_B(buf, 1); MFMA16(0);
        SBAR();
        READ_A(buf, 1, 1); MFMA16(1);
    }
    __syncthreads();   // K-loop LDS reads done everywhere; repurpose as image

    // ---------------- epilogue ----------------
    const int N = ph.seg[segi].N;
    const int mode = ph.seg[segi].mode;
    const int accum = ph.seg[segi].accum;
    const u16* rsrcbP = ph.seg[segi].rsrcb;
    const float* rsrcfP = ph.seg[segi].rsrcf;
    const float* biasP = ph.seg[segi].bias;
    const u16* esubP = ph.seg[segi].esub;
    float* outfP = ph.seg[segi].outf;
    u16* outbfP = ph.seg[segi].outbf;

    const int nb32 = N >> 5;
    auto regOffOf = [&](int ry, int rx) -> size_t {
        return ((size_t)(by2 * 2 + ry) * nb32 + (size_t)(bx2 * 2 + rx) * 4) * 4096;
    };

    const int slot = wr * 2 + (wc >> 1);       // which 128x128 region this wave owns
    u16* img = SH + slot * 16384;
    const size_t regOff = regOffOf(wr, wc >> 1);
    const u16* rsrcR = rsrcbP ? rsrcbP + regOff : nullptr;
    const u16* esubR = esubP ? esubP + regOff : nullptr;

    float lsum = 0.f;
    const int rowg0 = by2 * 256 + wr * 128 + q * 4;   // + mt*16 + r
    const int colg0 = bx2 * 256 + wc * 64;            // + nt*16 + ln

#pragma unroll
    for (int nt = 0; nt < 4; ++nt) {
        const int cl = (wc & 1) * 64 + nt * 16 + ln;
        const int colo = (cl >> 5) * 4096 + ((cl >> 3) & 3) * 1024 + (cl & 7);
        const int colg = colg0 + nt * 16 + ln;
        const float bnt = (mode == 0) ? biasP[colg] : 0.f;
#pragma unroll
        for (int mt = 0; mt < 8; ++mt) {
#pragma unroll
            for (int r = 0; r < 4; ++r) {
                const int o = colo + (mt * 16 + q * 4 + r) * 8;
                const float c = acc[mt][nt][r];
                float v;
                if (mode == 0) {
                    v = fast_tanh(c + bnt);
                    if (outfP) outfP[(size_t)(rowg0 + mt * 16 + r) * N + colg] = v;
                } else if (mode == 1) {
                    v = bf2f(rsrcR[o]) - fast_tanh(c);
                    lsum += v * v;
                } else if (mode == 2) {
                    v = bf2f(rsrcR[o]) + 0.1f * (c - bf2f(esubR[o]));
                } else {
                    const size_t idx = (size_t)(rowg0 + mt * 16 + r) * N + colg;
                    v = 0.9f * rsrcfP[idx] + 0.1f * c;
                    outfP[idx] = v;
                    lsum += v * v;
                }
                img[o] = f2bf(v);
            }
        }
    }
    __syncthreads();
    {   // coalesced store of the full 256x256 blocked image: 256B/thread
        const int slotS = tid >> 7;
        const int offS = (tid & 127) * 128;
        u16* outR = outbfP + regOffOf(slotS >> 1, slotS & 1) + offS;
        const u16* src = SH + slotS * 16384 + offS;
#pragma unroll
        for (int i = 0; i < 16; ++i)
            *(u16x8*)(outR + i * 8) = *(const u16x8*)(src + i * 8);
    }

    if (accum) {
        lsum *= 0.5f;
#pragma unroll
        for (int o = 32; o > 0; o >>= 1) lsum += __shfl_down(lsum, o);
        if (lane == 0) red[wave] = lsum;
        __syncthreads();
        if (tid == 0) {
            float s = 0.f;
#pragma unroll
            for (int i = 0; i < 8; ++i) s += red[i];
            atomicAdd(errAcc, s);
        }
    }
}

// ---------------- host ----------------

extern "C" void kernel_launch(void* const* d_in, const int* in_sizes, int n_in,
                              void* d_out, int out_size, void* d_ws, size_t ws_size,
                              hipStream_t stream) {
    const float* x  = (const float*)d_in[0];
    const float* W0 = (const float*)d_in[1];
    const float* b0 = (const float*)d_in[2];
    const float* W1 = (const float*)d_in[3];
    const float* b1 = (const float*)d_in[4];
    const float* W2 = (const float*)d_in[5];
    const float* b2 = (const float*)d_in[6];

    const int Bz = 4096;  // batch

    char* ws = (char*)d_ws;
    size_t off = 0;
    auto alloc = [&](size_t bytes) -> char* {
        char* p = ws + off;
        off += (bytes + 255) & ~(size_t)255;
        return p;
    };

    u16*   r1b = (u16*)  alloc((size_t)Bz * 2048 * 2);   // blocked, MASTER r1
    u16*   r2b = (u16*)  alloc((size_t)Bz * 2048 * 2);   // blocked, MASTER r2
    u16*   r3b = (u16*)  alloc((size_t)Bz * 512 * 2);    // blocked
    u16*   e0b = (u16*)  alloc((size_t)Bz * 1024 * 2);   // blocked
    u16*   e1b = (u16*)  alloc((size_t)Bz * 2048 * 2);   // blocked
    u16*   e2b = (u16*)  alloc((size_t)Bz * 2048 * 2);   // blocked
    u16*   xb  = (u16*)  alloc((size_t)Bz * 1024 * 2);   // blocked
    u16*   W0b = (u16*)  alloc((size_t)2048 * 1024 * 2);
    u16*   W0t = (u16*)  alloc((size_t)1024 * 2048 * 2);
    u16*   W1b = (u16*)  alloc((size_t)2048 * 2048 * 2);
    u16*   W1t = (u16*)  alloc((size_t)2048 * 2048 * 2);
    u16*   W2b = (u16*)  alloc((size_t)512 * 2048 * 2);
    u16*   W2t = (u16*)  alloc((size_t)2048 * 512 * 2);
    u16*   tmp = (u16*)  alloc((size_t)2048 * 2048 * 2); // row-major scratch

    float* r3f    = (float*)d_out;            // 4096 x 512, f32 MASTER r3
    float* errAcc = ((float*)d_out) + (size_t)Bz * 512;

    auto blkify = [&](const u16* s, u16* d, int M, int K) {
        blockify<<<(M / 128) * (K / 32), 256, 0, stream>>>(s, d, K);
    };

    cvt_bf16<<<(Bz * 1024 / 4) / 256, 256, 0, stream>>>(x, tmp, Bz * 1024 / 4);
    blkify(tmp, xb, Bz, 1024);
    cvt_bf16<<<(2048 * 1024 / 4) / 256, 256, 0, stream>>>(W0, tmp, 2048 * 1024 / 4);
    blkify(tmp, W0b, 2048, 1024);
    cvt_bf16<<<(2048 * 2048 / 4) / 256, 256, 0, stream>>>(W1, tmp, 2048 * 2048 / 4);
    blkify(tmp, W1b, 2048, 2048);
    cvt_bf16<<<(512 * 2048 / 4) / 256, 256, 0, stream>>>(W2, tmp, 512 * 2048 / 4);
    blkify(tmp, W2b, 512, 2048);
    transpose_cvt<<<dim3(1024 / 32, 2048 / 32), 256, 0, stream>>>(W0, tmp, 2048, 1024);
    blkify(tmp, W0t, 1024, 2048);
    transpose_cvt<<<dim3(2048 / 32, 2048 / 32), 256, 0, stream>>>(W1, tmp, 2048, 2048);
    blkify(tmp, W1t, 2048, 2048);
    transpose_cvt<<<dim3(2048 / 32, 512 / 32),  256, 0, stream>>>(W2, tmp, 512, 2048);
    blkify(tmp, W2t, 2048, 512);

    hipMemsetAsync(errAcc, 0, 4, stream);

    auto mkseg = [&](const u16* A, const u16* B, int K, int N,
                     const u16* rsrcb, const float* rsrcf, const float* bias,
                     const u16* esub, float* outf, u16* outbf,
                     int mode, int accum) {
        Seg s;
        s.A = A; s.B = B; s.rsrcb = rsrcb; s.rsrcf = rsrcf; s.bias = bias;
        s.esub = esub; s.outf = outf; s.outbf = outbf;
        s.K = K; s.N = N; s.blkStart = 0; s.mode = mode; s.accum = accum;
        return s;
    };
    auto nblk = [&](int N) { return (N / 256) * (Bz / 256); };

    auto launch1 = [&](Seg s0) {
        Phase ph;
        int b0c = nblk(s0.N);
        ph.seg[0] = s0; ph.seg[1] = s0; ph.seg[2] = s0;
        ph.bEnd0 = b0c; ph.bEnd1 = b0c;
        pc_phase<<<b0c, 512, 0, stream>>>(ph, errAcc);
    };
    auto launch3 = [&](Seg s0, Seg s1, Seg s2) {
        Phase ph;
        int b0c = nblk(s0.N), b1c = nblk(s1.N), b2c = nblk(s2.N);
        s1.blkStart = b0c; s2.blkStart = b0c + b1c;
        ph.seg[0] = s0; ph.seg[1] = s1; ph.seg[2] = s2;
        ph.bEnd0 = b0c; ph.bEnd1 = b0c + b1c;
        pc_phase<<<b0c + b1c + b2c, 512, 0, stream>>>(ph, errAcc);
    };

    // forward init (sequential dependency)
    launch1(mkseg(xb,  W0b, 1024, 2048, nullptr, nullptr, b0, nullptr, nullptr, r1b, 0, 0));
    launch1(mkseg(r1b, W1b, 2048, 2048, nullptr, nullptr, b1, nullptr, nullptr, r2b, 0, 0));
    launch1(mkseg(r2b, W2b, 2048, 512,  nullptr, nullptr, b2, nullptr, r3f,     r3b, 0, 0));

    // 20 relaxation steps
    for (int s = 0; s < 20; ++s) {
        int last = (s == 19) ? 1 : 0;
        // errors (independent; read old state)
        launch3(mkseg(r2b, W1t, 2048, 2048, r1b, nullptr, nullptr, nullptr, nullptr, e1b, 1, 0),
                mkseg(r1b, W0t, 2048, 1024, xb,  nullptr, nullptr, nullptr, nullptr, e0b, 1, 0),
                mkseg(r3b, W2t, 512,  2048, r2b, nullptr, nullptr, nullptr, nullptr, e2b, 1, 0));
        // updates (independent; in-place on bf16 masters)
        launch3(mkseg(e1b, W1b, 2048, 2048, r2b, nullptr, nullptr, e2b, nullptr, r2b, 2, 0),
                mkseg(e2b, W2b, 2048, 512,  nullptr, r3f, nullptr, nullptr, r3f,  r3b, 3, last),
                mkseg(e0b, W0b, 1024, 2048, r1b, nullptr, nullptr, e1b, nullptr, r1b, 2, 0));
    }

    // final errors with 0.5*sum(e^2) accumulation (r3^2 added by last UPD3)
    launch3(mkseg(r2b, W1t, 2048, 2048, r1b, nullptr, nullptr, nullptr, nullptr, e1b, 1, 1),
            mkseg(r1b, W0t, 2048, 1024, xb,  nullptr, nullptr, nullptr, nullptr, e0b, 1, 1),
            mkseg(r3b, W2t, 512,  2048, r2b, nullptr, nullptr, nullptr, nullptr, e2b, 1, 1));
}

// Round 2
// 3604.995 us; speedup vs baseline: 1.6027x; 1.6027x over previous
//
#include <hip/hip_runtime.h>

typedef unsigned short u16;
typedef __bf16 bf16_t;
typedef bf16_t bf16x8 __attribute__((ext_vector_type(8)));
typedef u16 u16x8 __attribute__((ext_vector_type(8)));
typedef float f32x4 __attribute__((ext_vector_type(4)));

__device__ __forceinline__ u16 f2bf(float f) {
    unsigned u = __builtin_bit_cast(unsigned, f);
    u += 0x7fffu + ((u >> 16) & 1u);   // RNE
    return (u16)(u >> 16);
}
__device__ __forceinline__ float bf2f(u16 h) {
    unsigned u = ((unsigned)h) << 16;
    return __builtin_bit_cast(float, u);
}
__device__ __forceinline__ float fast_tanh(float x) {
    x = fminf(fmaxf(x, -20.f), 20.f);
    float e = __expf(2.f * x);
    return (e - 1.f) * __builtin_amdgcn_rcpf(e + 1.f);
}
__device__ __forceinline__ void gload_lds16(const void* g, void* l) {
    __builtin_amdgcn_global_load_lds((__attribute__((address_space(1))) void*)(g),
                                     (__attribute__((address_space(3))) void*)(l),
                                     16, 0, 0);
}
__device__ __forceinline__ bf16x8 ld8(const u16* p) {
    return __builtin_bit_cast(bf16x8, *(const u16x8*)p);
}

// s_waitcnt immediates (validated on this harness): vmcnt low bits [3:0],
// all other count fields "no wait".
#define VMW4() __builtin_amdgcn_s_waitcnt(0x3F74)
#define VMW0() __builtin_amdgcn_s_waitcnt(0x3F70)
#define MEMFENCE() asm volatile("" ::: "memory")

// m201-style phase gating: opening barrier AFTER {ds_read, stage} issue, then
// lgkmcnt(0) + sched_barrier(0) (rule #18: hipcc hoists register-only MFMA past
// inline-asm waits otherwise), MFMA cluster, closing barrier (also pinned).
#define GATE() do { \
    MEMFENCE(); __builtin_amdgcn_s_barrier(); \
    asm volatile("s_waitcnt lgkmcnt(0)" ::: "memory"); \
    __builtin_amdgcn_sched_barrier(0); \
} while (0)
#define CLOSE() do { \
    __builtin_amdgcn_sched_barrier(0); \
    MEMFENCE(); __builtin_amdgcn_s_barrier(); MEMFENCE(); \
} while (0)

// Blocked layout: M x N stored as 128x32 tiles, tile (m>>7,n>>5) contiguous
// 4096 elems; interior [kb=(n>>3)&3][row=m&127][n&7] == the LDS staging image.

// ---------------- conversion kernels ----------------

__global__ void cvt_bf16(const float* __restrict__ src, u16* __restrict__ dst, int n4) {
    int i = blockIdx.x * blockDim.x + threadIdx.x;
    if (i < n4) {
        float4 v = ((const float4*)src)[i];
        ushort4 o;
        o.x = f2bf(v.x); o.y = f2bf(v.y); o.z = f2bf(v.z); o.w = f2bf(v.w);
        ((ushort4*)dst)[i] = o;
    }
}

// W: R x C fp32  ->  WT: C x R bf16 (row-major)
__global__ void transpose_cvt(const float* __restrict__ W, u16* __restrict__ WT, int R, int C) {
    __shared__ float tile[32][33];
    int c0 = blockIdx.x * 32, r0 = blockIdx.y * 32;
    int tx = threadIdx.x & 31, ty = threadIdx.x >> 5;  // 32x8
#pragma unroll
    for (int i = 0; i < 32; i += 8)
        tile[ty + i][tx] = W[(size_t)(r0 + ty + i) * C + (c0 + tx)];
    __syncthreads();
#pragma unroll
    for (int i = 0; i < 32; i += 8)
        WT[(size_t)(c0 + ty + i) * R + (r0 + tx)] = f2bf(tile[tx][ty + i]);
}

// row-major bf16 (M x K) -> blocked layout. grid = (M/128)*(K/32), 256 thr.
__global__ void blockify(const u16* __restrict__ src, u16* __restrict__ dst, int K) {
    const int nk = K >> 5;
    const int rb = blockIdx.x / nk, cb = blockIdx.x % nk;
    const int t = threadIdx.x;
    const int kloc = (t & 7) * 4;
    u16* d = dst + (size_t)blockIdx.x * 4096 + ((kloc >> 3) << 10) + (kloc & 7);
    const u16* s = src + (size_t)(rb * 128) * K + cb * 32 + kloc;
#pragma unroll
    for (int p = 0; p < 4; ++p) {
        int row = (t >> 3) + p * 32;
        *(ushort4*)(d + row * 8) = *(const ushort4*)(s + (size_t)row * K);
    }
}

// ---------------- segmented fused NT GEMM phase ----------------
// 256x256 tile, 8 waves (2M x 4N), BK=64, double-buffered 128KB LDS.
// Per K-tile: 4 gated phases; stages (2 gload_lds each) issued 1 per phase;
// counted vmcnt(4) at the two K-half boundaries (never drained mid-loop).
// mode 0 (FWD):  v = tanh(C + bias[n]);            -> outbf [+outf]
// mode 1 (ERR):  v = rsrcb - tanh(C);              -> outbf  (+0.5v^2)
// mode 2 (UPD):  v = rsrcb + 0.1*(C - esub);       -> outbf (in-place ok)
// mode 3 (UPD3): v = 0.9*rsrcf + 0.1*C;            -> outf, outbf (+0.5v^2)

struct Seg {
    const u16* A; const u16* B;
    const u16* rsrcb;          // blocked bf16 (modes 1,2)
    const float* rsrcf;        // f32 row-major (mode 3)
    const float* bias;         // f32 (mode 0)
    const u16* esub;           // blocked bf16 (mode 2)
    float* outf;               // f32 row-major (modes 0(r3),3)
    u16* outbf;                // blocked bf16 (all modes)
    int K, N, blkStart, mode, accum;
};
struct Phase {
    Seg seg[3];
    int bEnd0, bEnd1;
};

#define READ_A(buf, kk, mh) do { \
    const u16* _p = SH + (buf)*16384 + (wr2+(kk))*4096 + aoff + (mh)*512; \
    aR[0] = ld8(_p); aR[1] = ld8(_p+128); aR[2] = ld8(_p+256); aR[3] = ld8(_p+384); \
} while (0)

#define READ_B(buf, kk) do { \
    const u16* _p = SH + 32768 + (buf)*16384 + (wch2+(kk))*4096 + boff; \
    bR[0] = ld8(_p); bR[1] = ld8(_p+128); bR[2] = ld8(_p+256); bR[3] = ld8(_p+384); \
} while (0)

#define MFMA16(mh) do { \
    __builtin_amdgcn_s_setprio(1); \
    _Pragma("unroll") \
    for (int _i = 0; _i < 4; ++_i) { \
        _Pragma("unroll") \
        for (int _n = 0; _n < 4; ++_n) \
            acc[(mh)*4+_i][_n] = __builtin_amdgcn_mfma_f32_16x16x32_bf16( \
                aR[_i], bR[_n], acc[(mh)*4+_i][_n], 0, 0, 0); \
    } \
    __builtin_amdgcn_s_setprio(0); \
} while (0)

// One gated phase: {reads, stage} -> barrier -> lgkm0 -> MFMA -> [vmcnt] -> barrier
#define DO_PHASE(kk, mh, RB, STAGE_STMT, WAIT_STMT) do { \
    READ_A(buf, kk, mh); \
    if (RB) READ_B(buf, kk); \
    STAGE_STMT; \
    GATE(); \
    MFMA16(mh); \
    WAIT_STMT; \
    CLOSE(); \
} while (0)

__global__ __launch_bounds__(512, 2) void pc_phase(Phase ph, float* __restrict__ errAcc) {
    // [0..32768)  A tiles: 2 buf x {ks,A-half} blocks x 4096
    // [32768..65536) B tiles, same. Epilogue reuses as 8 wave-private 16KB slices.
    __shared__ __align__(16) u16 SH[65536];
    __shared__ float red[8];

    const int bid = blockIdx.x;
    const int segi = (bid >= ph.bEnd0 ? 1 : 0) + (bid >= ph.bEnd1 ? 1 : 0);

    const u16* Ab = ph.seg[segi].A;
    const u16* Bb = ph.seg[segi].B;
    const int K = ph.seg[segi].K;
    const int local = bid - ph.seg[segi].blkStart;
    const int bx2 = local >> 4;      // N-tile (weight-major grouping, 16 M-tiles/group)
    const int by2 = local & 15;      // M-tile
    const int nk32 = K >> 5, NT = K >> 6;

    const int tid  = threadIdx.x;
    const int wave = tid >> 6, lane = tid & 63;
    const int q    = lane >> 4, ln = lane & 15;
    const int wr = wave >> 2, wc = wave & 3;      // 2M x 4N wave grid
    const int wr2 = wr * 2, wch2 = (wc >> 1) * 2;
    const int aoff = q * 1024 + ln * 8;
    const int boff = q * 1024 + ((wc & 1) * 64 + ln) * 8;

    const size_t t8 = (size_t)tid * 8;
    const u16* gA0 = Ab + ((size_t)(by2 * 2 + 0) * nk32) * 4096 + t8;
    const u16* gA1 = Ab + ((size_t)(by2 * 2 + 1) * nk32) * 4096 + t8;
    const u16* gB0 = Bb + ((size_t)(bx2 * 2 + 0) * nk32) * 4096 + t8;
    const u16* gB1 = Bb + ((size_t)(bx2 * 2 + 1) * nk32) * 4096 + t8;
    const int wb = wave * 512;

    auto stageA = [&](int cb, int bf, int ks) {
        const size_t g = (size_t)cb * 4096;
        u16* a = SH + bf * 16384 + ks * 4096 + wb;
        gload_lds16(gA0 + g, a);
        gload_lds16(gA1 + g, a + 8192);
    };
    auto stageB = [&](int cb, int bf, int ks) {
        const size_t g = (size_t)cb * 4096;
        u16* b = SH + 32768 + bf * 16384 + ks * 4096 + wb;
        gload_lds16(gB0 + g, b);
        gload_lds16(gB1 + g, b + 8192);
    };

    f32x4 acc[8][4];
#pragma unroll
    for (int i = 0; i < 8; ++i)
#pragma unroll
        for (int j = 0; j < 4; ++j)
            acc[i][j] = (f32x4){0.f, 0.f, 0.f, 0.f};

    // prologue: stage tile 0 fully into buf0 (8 loads); wait its ks0 half.
    stageA(0, 0, 0); stageB(0, 0, 0);
    stageA(1, 0, 1); stageB(1, 0, 1);
    VMW4();
    MEMFENCE(); __builtin_amdgcn_s_barrier(); MEMFENCE();

    bf16x8 aR[4], bR[4];

    for (int t = 0; t < NT - 1; ++t) {
        const int buf = t & 1, nbuf = buf ^ 1;
        const int cb0 = 2 * t + 2, cb1 = 2 * t + 3;
        DO_PHASE(0, 0, 1, stageA(cb0, nbuf, 0), (void)0);
        DO_PHASE(0, 1, 0, stageB(cb0, nbuf, 0), VMW4());   // ks1(t) landed; ks0(t+1) in flight
        DO_PHASE(1, 0, 1, stageA(cb1, nbuf, 1), (void)0);
        DO_PHASE(1, 1, 0, stageB(cb1, nbuf, 1), VMW4());   // ks0(t+1) landed; ks1(t+1) in flight
    }
    {   // tail tile: no staging; P2 must drain (nothing newer in flight)
        const int buf = (NT - 1) & 1;
        DO_PHASE(0, 0, 1, (void)0, (void)0);
        DO_PHASE(0, 1, 0, (void)0, VMW0());
        DO_PHASE(1, 0, 1, (void)0, (void)0);
        DO_PHASE(1, 1, 0, (void)0, (void)0);
    }
    __syncthreads();   // K-loop LDS reads done everywhere; repurpose as slices

    // ---------------- epilogue (wave-private; no barriers) ----------------
    const int N = ph.seg[segi].N;
    const int mode = ph.seg[segi].mode;
    const int accum = ph.seg[segi].accum;
    const u16* rsrcbP = ph.seg[segi].rsrcb;
    const float* rsrcfP = ph.seg[segi].rsrcf;
    const float* biasP = ph.seg[segi].bias;
    const u16* esubP = ph.seg[segi].esub;
    float* outfP = ph.seg[segi].outf;
    u16* outbfP = ph.seg[segi].outbf;

    const int nb32 = N >> 5;
    // wave's 128x64 output: region (by2*2+wr, bx2*2+(wc>>1)), col-half wc&1
    const size_t regOff = ((size_t)(by2 * 2 + wr) * nb32 + (size_t)(bx2 * 2 + (wc >> 1)) * 4) * 4096;
    u16* SLICE = SH + wave * 8192;   // 16KB per wave

    float lsum = 0.f;
    const int rowg0 = by2 * 256 + wr * 128 + q * 4;   // + mt*16 + r
    const int colg0 = bx2 * 256 + wc * 64;            // + nt*16 + ln

#pragma unroll
    for (int ct = 0; ct < 2; ++ct) {
        const size_t tileOff = regOff + (size_t)((wc & 1) * 2 + ct) * 4096;
        if (mode == 1 || mode == 2) {
#pragma unroll
            for (int p = 0; p < 8; ++p)
                *(u16x8*)(SLICE + p * 512 + lane * 8) =
                    *(const u16x8*)(rsrcbP + tileOff + p * 512 + lane * 8);
        }
        if (mode == 2) {
#pragma unroll
            for (int p = 0; p < 8; ++p)
                *(u16x8*)(SLICE + 4096 + p * 512 + lane * 8) =
                    *(const u16x8*)(esubP + tileOff + p * 512 + lane * 8);
        }
#pragma unroll
        for (int nh = 0; nh < 2; ++nh) {
            const int nt = ct * 2 + nh;
            const int ci = nh * 16 + ln;                    // within-tile col
            const int co = ((ci >> 3) & 3) * 1024 + (ci & 7);
            const int colg = colg0 + nt * 16 + ln;
            const float bnt = (mode == 0) ? biasP[colg] : 0.f;
#pragma unroll
            for (int mt = 0; mt < 8; ++mt) {
#pragma unroll
                for (int r = 0; r < 4; ++r) {
                    const int row = mt * 16 + q * 4 + r;
                    const int o = co + row * 8;
                    const float c = acc[mt][nt][r];
                    float v;
                    if (mode == 0) {
                        v = fast_tanh(c + bnt);
                        if (outfP) outfP[(size_t)(rowg0 + mt * 16 + r) * N + colg] = v;
                    } else if (mode == 1) {
                        v = bf2f(SLICE[o]) - fast_tanh(c);
                        if (accum) lsum += v * v;
                    } else if (mode == 2) {
                        v = bf2f(SLICE[o]) + 0.1f * (c - bf2f(SLICE[4096 + o]));
                    } else {
                        const size_t idx = (size_t)(rowg0 + mt * 16 + r) * N + colg;
                        v = 0.9f * rsrcfP[idx] + 0.1f * c;
                        outfP[idx] = v;
                        if (accum) lsum += v * v;
                    }
                    SLICE[o] = f2bf(v);
                }
            }
        }
#pragma unroll
        for (int p = 0; p < 8; ++p)
            *(u16x8*)(outbfP + tileOff + p * 512 + lane * 8) =
                *(const u16x8*)(SLICE + p * 512 + lane * 8);
    }

    if (accum) {
        lsum *= 0.5f;
#pragma unroll
        for (int o = 32; o > 0; o >>= 1) lsum += __shfl_down(lsum, o);
        if (lane == 0) red[wave] = lsum;
        __syncthreads();
        if (tid == 0) {
            float s = 0.f;
#pragma unroll
            for (int i = 0; i < 8; ++i) s += red[i];
            atomicAdd(errAcc, s);
        }
    }
}

// ---------------- host ----------------

extern "C" void kernel_launch(void* const* d_in, const int* in_sizes, int n_in,
                              void* d_out, int out_size, void* d_ws, size_t ws_size,
                              hipStream_t stream) {
    const float* x  = (const float*)d_in[0];
    const float* W0 = (const float*)d_in[1];
    const float* b0 = (const float*)d_in[2];
    const float* W1 = (const float*)d_in[3];
    const float* b1 = (const float*)d_in[4];
    const float* W2 = (const float*)d_in[5];
    const float* b2 = (const float*)d_in[6];

    const int Bz = 4096;  // batch

    char* ws = (char*)d_ws;
    size_t off = 0;
    auto alloc = [&](size_t bytes) -> char* {
        char* p = ws + off;
        off += (bytes + 255) & ~(size_t)255;
        return p;
    };

    u16*   r1b = (u16*)  alloc((size_t)Bz * 2048 * 2);   // blocked, MASTER r1
    u16*   r2b = (u16*)  alloc((size_t)Bz * 2048 * 2);   // blocked, MASTER r2
    u16*   r3b = (u16*)  alloc((size_t)Bz * 512 * 2);    // blocked
    u16*   e0b = (u16*)  alloc((size_t)Bz * 1024 * 2);   // blocked
    u16*   e1b = (u16*)  alloc((size_t)Bz * 2048 * 2);   // blocked
    u16*   e2b = (u16*)  alloc((size_t)Bz * 2048 * 2);   // blocked
    u16*   xb  = (u16*)  alloc((size_t)Bz * 1024 * 2);   // blocked
    u16*   W0b = (u16*)  alloc((size_t)2048 * 1024 * 2);
    u16*   W0t = (u16*)  alloc((size_t)1024 * 2048 * 2);
    u16*   W1b = (u16*)  alloc((size_t)2048 * 2048 * 2);
    u16*   W1t = (u16*)  alloc((size_t)2048 * 2048 * 2);
    u16*   W2b = (u16*)  alloc((size_t)512 * 2048 * 2);
    u16*   W2t = (u16*)  alloc((size_t)2048 * 512 * 2);
    u16*   tmp = (u16*)  alloc((size_t)2048 * 2048 * 2); // row-major scratch

    float* r3f    = (float*)d_out;            // 4096 x 512, f32 MASTER r3
    float* errAcc = ((float*)d_out) + (size_t)Bz * 512;

    auto blkify = [&](const u16* s, u16* d, int M, int K) {
        blockify<<<(M / 128) * (K / 32), 256, 0, stream>>>(s, d, K);
    };

    cvt_bf16<<<(Bz * 1024 / 4) / 256, 256, 0, stream>>>(x, tmp, Bz * 1024 / 4);
    blkify(tmp, xb, Bz, 1024);
    cvt_bf16<<<(2048 * 1024 / 4) / 256, 256, 0, stream>>>(W0, tmp, 2048 * 1024 / 4);
    blkify(tmp, W0b, 2048, 1024);
    cvt_bf16<<<(2048 * 2048 / 4) / 256, 256, 0, stream>>>(W1, tmp, 2048 * 2048 / 4);
    blkify(tmp, W1b, 2048, 2048);
    cvt_bf16<<<(512 * 2048 / 4) / 256, 256, 0, stream>>>(W2, tmp, 512 * 2048 / 4);
    blkify(tmp, W2b, 512, 2048);
    transpose_cvt<<<dim3(1024 / 32, 2048 / 32), 256, 0, stream>>>(W0, tmp, 2048, 1024);
    blkify(tmp, W0t, 1024, 2048);
    transpose_cvt<<<dim3(2048 / 32, 2048 / 32), 256, 0, stream>>>(W1, tmp, 2048, 2048);
    blkify(tmp, W1t, 2048, 2048);
    transpose_cvt<<<dim3(2048 / 32, 512 / 32),  256, 0, stream>>>(W2, tmp, 512, 2048);
    blkify(tmp, W2t, 2048, 512);

    hipMemsetAsync(errAcc, 0, 4, stream);

    auto mkseg = [&](const u16* A, const u16* B, int K, int N,
                     const u16* rsrcb, const float* rsrcf, const float* bias,
                     const u16* esub, float* outf, u16* outbf,
                     int mode, int accum) {
        Seg s;
        s.A = A; s.B = B; s.rsrcb = rsrcb; s.rsrcf = rsrcf; s.bias = bias;
        s.esub = esub; s.outf = outf; s.outbf = outbf;
        s.K = K; s.N = N; s.blkStart = 0; s.mode = mode; s.accum = accum;
        return s;
    };
    auto nblk = [&](int N) { return (N / 256) * (Bz / 256); };

    auto launch1 = [&](Seg s0) {
        Phase ph;
        int b0c = nblk(s0.N);
        ph.seg[0] = s0; ph.seg[1] = s0; ph.seg[2] = s0;
        ph.bEnd0 = b0c; ph.bEnd1 = b0c;
        pc_phase<<<b0c, 512, 0, stream>>>(ph, errAcc);
    };
    auto launch3 = [&](Seg s0, Seg s1, Seg s2) {
        Phase ph;
        int b0c = nblk(s0.N), b1c = nblk(s1.N), b2c = nblk(s2.N);
        s1.blkStart = b0c; s2.blkStart = b0c + b1c;
        ph.seg[0] = s0; ph.seg[1] = s1; ph.seg[2] = s2;
        ph.bEnd0 = b0c; ph.bEnd1 = b0c + b1c;
        pc_phase<<<b0c + b1c + b2c, 512, 0, stream>>>(ph, errAcc);
    };

    // forward init (sequential dependency)
    launch1(mkseg(xb,  W0b, 1024, 2048, nullptr, nullptr, b0, nullptr, nullptr, r1b, 0, 0));
    launch1(mkseg(r1b, W1b, 2048, 2048, nullptr, nullptr, b1, nullptr, nullptr, r2b, 0, 0));
    launch1(mkseg(r2b, W2b, 2048, 512,  nullptr, nullptr, b2, nullptr, r3f,     r3b, 0, 0));

    // 20 relaxation steps
    for (int s = 0; s < 20; ++s) {
        int last = (s == 19) ? 1 : 0;
        // errors (independent; read old state)
        launch3(mkseg(r2b, W1t, 2048, 2048, r1b, nullptr, nullptr, nullptr, nullptr, e1b, 1, 0),
                mkseg(r1b, W0t, 2048, 1024, xb,  nullptr, nullptr, nullptr, nullptr, e0b, 1, 0),
                mkseg(r3b, W2t, 512,  2048, r2b, nullptr, nullptr, nullptr, nullptr, e2b, 1, 0));
        // updates (independent; in-place on bf16 masters)
        launch3(mkseg(e1b, W1b, 2048, 2048, r2b, nullptr, nullptr, e2b, nullptr, r2b, 2, 0),
                mkseg(e2b, W2b, 2048, 512,  nullptr, r3f, nullptr, nullptr, r3f,  r3b, 3, last),
                mkseg(e0b, W0b, 1024, 2048, r1b, nullptr, nullptr, e1b, nullptr, r1b, 2, 0));
    }

    // final errors with 0.5*sum(e^2) accumulation (r3^2 added by last UPD3)
    launch3(mkseg(r2b, W1t, 2048, 2048, r1b, nullptr, nullptr, nullptr, nullptr, e1b, 1, 1),
            mkseg(r1b, W0t, 2048, 1024, xb,  nullptr, nullptr, nullptr, nullptr, e0b, 1, 1),
            mkseg(r3b, W2t, 512,  2048, r2b, nullptr, nullptr, nullptr, nullptr, e2b, 1, 1));
}